// Round 6
// baseline (859.875 us; speedup 1.0000x reference)
//
#include <hip/hip_runtime.h>
#include <stdint.h>

// Problem dims
#define NB  256
#define NT  100
#define NIN 128
#define NH  1024
#define NOUT 35
#define MT  112             // time rows padded to 7*16 for MFMA M-tiles

// d_out float offsets
#define O_SPK2 26214400ull
#define O_SPK3 52428800ull
#define O_SPK4 78643200ull
#define O_MEM4 79539200ull

// ws byte offsets
#define WS_SPK0 0ull                  // 256*112*1024 spike bytes [b][t][k]
#define WS_SPK1 29360128ull           // ping-pong buffer
#define WS_K2B  58720256ull           // 1024*1024 i8
#define WS_K3B  59768832ull           // 1024*1024 i8
#define WS_K4B  60817408ull           // 48*1024 i8 (rows 35..47 zero)
#define WS_Q1T  60866560ull           // 128*1024 f32
#define WS_N1   61390848ull           // 25600 u32
// end ~59 MB

#define S2C ((float)((1.0 - 0.001) / 15.0))
#define S1C ((float)(1.0 / 15.0))

typedef int v4i __attribute__((ext_vector_type(4)));

__device__ __forceinline__ void async16(const void* g, void* l) {
  __builtin_amdgcn_global_load_lds((const __attribute__((address_space(1))) uint32_t*)g,
                                   (__attribute__((address_space(3))) uint32_t*)l, 16, 0, 0);
}

__device__ __forceinline__ uint8_t qk(float w) {
  float wc = fminf(fmaxf(w, 0.001f), 1.0f);
  return (uint8_t)(int)rintf((wc - 0.001f) / S2C);
}

// ------------------------------------------------------------------
// K1: weight quantization (coalesced) + q1T f32 + zero n1
// ------------------------------------------------------------------
__global__ void k_prep(const float* __restrict__ w1, const float* __restrict__ w2,
                       const float* __restrict__ w3, const float* __restrict__ w4,
                       uint8_t* __restrict__ ws)
{
  long long id = (long long)blockIdx.x * 256 + threadIdx.x;
  if (id < 1048576) { ws[WS_K2B + id] = qk(w2[id]); return; }
  id -= 1048576;
  if (id < 1048576) { ws[WS_K3B + id] = qk(w3[id]); return; }
  id -= 1048576;
  if (id < 49152) {
    int j = (int)(id >> 10), i = (int)(id & 1023);
    ws[WS_K4B + id] = (j < NOUT) ? qk(w4[(size_t)j * 1024 + i]) : (uint8_t)0;
    return;
  }
  id -= 49152;
  if (id < 131072) {
    int i = (int)(id >> 10), j = (int)(id & 1023);
    float wv = w1[(size_t)j * 128 + i];
    float wc = fminf(fmaxf(wv, -0.5f), 0.5f);
    float q = rintf((wc + 0.5f) / S1C) * S1C - 0.5f;
    ((float*)(ws + WS_Q1T))[id] = q;
    return;
  }
  id -= 131072;
  if (id < 25600) ((uint32_t*)(ws + WS_N1))[id] = 0;
}

// ------------------------------------------------------------------
// K2: cur1 fp32 GEMM (unchanged, verified bit-exact)
// ------------------------------------------------------------------
__global__ __launch_bounds__(256) void k_cur1(const float* __restrict__ x,
                                              const uint8_t* __restrict__ ws,
                                              float* __restrict__ out)
{
  __shared__ float xsT[128 * 68];
  __shared__ float qch[16 * 256];
  const float* q1T = (const float*)(ws + WS_Q1T);
  const int tid = threadIdx.x;
  const int rb = blockIdx.x >> 2, cb = blockIdx.x & 3;
  const int t = rb >> 2, b0 = (rb & 3) * 64;
  const int jI = tid & 63, rI = tid >> 6;
  const int j4 = jI * 4, r16 = rI * 16;

  #pragma unroll
  for (int k = 0; k < 32; ++k) {
    int e = tid + k * 256;
    int r = e >> 7, i = e & 127;
    xsT[i * 68 + r] = x[((size_t)(b0 + r) * NT + t) * NIN + i] / 15.0f;
  }
  float acc[16][4];
  #pragma unroll
  for (int d = 0; d < 16; ++d) { acc[d][0]=0.f; acc[d][1]=0.f; acc[d][2]=0.f; acc[d][3]=0.f; }
  for (int ic = 0; ic < 8; ++ic) {
    __syncthreads();
    #pragma unroll
    for (int k = 0; k < 16; ++k) {
      int e = tid + k * 256;
      int ii = e >> 8, j = e & 255;
      qch[ii * 256 + j] = q1T[((size_t)(ic * 16 + ii) << 10) + cb * 256 + j];
    }
    __syncthreads();
    #pragma unroll
    for (int ii = 0; ii < 16; ++ii) {
      int i = ic * 16 + ii;
      const float4 q  = *(const float4*)&qch[ii * 256 + j4];
      const float4 xa = *(const float4*)&xsT[i * 68 + r16];
      const float4 xb = *(const float4*)&xsT[i * 68 + r16 + 4];
      const float4 xc = *(const float4*)&xsT[i * 68 + r16 + 8];
      const float4 xd = *(const float4*)&xsT[i * 68 + r16 + 12];
      float xr[16];
      xr[0]=xa.x; xr[1]=xa.y; xr[2]=xa.z; xr[3]=xa.w;
      xr[4]=xb.x; xr[5]=xb.y; xr[6]=xb.z; xr[7]=xb.w;
      xr[8]=xc.x; xr[9]=xc.y; xr[10]=xc.z; xr[11]=xc.w;
      xr[12]=xd.x; xr[13]=xd.y; xr[14]=xd.z; xr[15]=xd.w;
      #pragma unroll
      for (int d = 0; d < 16; ++d) {
        acc[d][0] = fmaf(xr[d], q.x, acc[d][0]);
        acc[d][1] = fmaf(xr[d], q.y, acc[d][1]);
        acc[d][2] = fmaf(xr[d], q.z, acc[d][2]);
        acc[d][3] = fmaf(xr[d], q.w, acc[d][3]);
      }
    }
  }
  #pragma unroll
  for (int d = 0; d < 16; ++d) {
    float4 v = make_float4(acc[d][0], acc[d][1], acc[d][2], acc[d][3]);
    *(float4*)&out[((size_t)rb * 64 + r16 + d) * 1024 + cb * 256 + j4] = v;
  }
}

// ------------------------------------------------------------------
// K3: layer-1 scan (unchanged): spk1 floats + spike bytes + n1
// ------------------------------------------------------------------
__global__ __launch_bounds__(256) void k_scan1(uint8_t* __restrict__ ws, float* __restrict__ out)
{
  const int tid = threadIdx.x;
  const int b = blockIdx.x >> 2;
  const int j = (blockIdx.x & 3) * 256 + tid;
  uint8_t* spk0 = ws + WS_SPK0;
  uint32_t* n1 = (uint32_t*)(ws + WS_N1);
  const size_t stride = (size_t)NB * NH;
  size_t idx = (size_t)b * NH + j;
  size_t sidx = (size_t)b * MT * 1024 + j;
  float m = 0.f;
  float c = out[idx];
  for (int t = 0; t < NT; ++t) {
    float cn = (t + 1 < NT) ? out[idx + stride] : 0.f;
    float rst = m > 1.0f ? 1.0f : 0.0f;
    m = fmaf(0.9f, m, c) - rst;
    bool sp = (m - 1.0f) > 0.0f;
    out[idx] = sp ? 1.0f : 0.0f;
    spk0[sidx] = sp ? 1 : 0;
    unsigned long long bal = __ballot(sp);
    if ((tid & 63) == 0) atomicAdd((unsigned int*)&n1[t * NB + b], (unsigned)__popcll(bal));
    idx += stride; sidx += 1024; c = cn;
  }
  for (int t = NT; t < MT; ++t) { spk0[sidx] = 0; sidx += 1024; }
}

// ------------------------------------------------------------------
// K4: persistent per-b kernel for layers 2,3,4.
//     Per hidden layer: 8 n-groups of 128; K-loop 8 chunks of 128 with
//     double-buffered async staging; C->LDS [j][t]; register-preloaded
//     scan; local n via ballot (no atomics/global n round-trip).
// ------------------------------------------------------------------
__global__ __launch_bounds__(256, 1) void k_l234(uint8_t* __restrict__ ws, float* __restrict__ out)
{
  __shared__ __align__(16) uint8_t lds[91328];
  uint8_t*  sAB     = lds;                         // 2 x 30720 (A 14 chunks | B 16 chunks)
  uint16_t* cbuf16  = (uint16_t*)(lds + 61440);    // [128 j][114 t] u16
  uint16_t* nprev16 = (uint16_t*)(lds + 90624);    // [112]
  uint32_t* nnextL  = (uint32_t*)(lds + 90880);    // [112]

  const int b = blockIdx.x;
  const int tid = threadIdx.x, lane = tid & 63, wave = tid >> 6;
  const int lm = lane & 15, lk = lane >> 4;

  uint8_t* SPK0b = ws + WS_SPK0 + (size_t)b * MT * 1024;
  uint8_t* SPK1b = ws + WS_SPK1 + (size_t)b * MT * 1024;
  const uint32_t* n1g = (const uint32_t*)(ws + WS_N1);

  if (tid < NT) nprev16[tid] = (uint16_t)n1g[tid * NB + b];
  if (tid >= NT && tid < MT) nprev16[tid] = 0;
  if (tid < MT) nnextL[tid] = 0;

  // stage chunk set (A rows of Ab, B rows ng*128.. of Bb) for k-chunk kc into buf p
  auto stage = [&](int p, const uint8_t* Ab, const uint8_t* Bb, int ng, int kc, int nB) {
    uint8_t* base = sAB + p * 30720;
    #pragma unroll
    for (int q = 0; q < 8; ++q) {
      int cid = wave * 8 + q;
      if (cid < 14) {
        int mt = cid >> 1, kh = cid & 1;
        async16(Ab + (size_t)(mt * 16 + lm) * 1024 + kc * 128 + kh * 64 + lk * 16,
                base + cid * 1024);
      } else if (cid < 14 + nB) {
        int c2 = cid - 14, nt = c2 >> 1, kh = c2 & 1;
        async16(Bb + (size_t)(ng * 128 + nt * 16 + lm) * 1024 + kc * 128 + kh * 64 + lk * 16,
                base + cid * 1024);
      }
    }
  };

  // -------- hidden layer (2 or 3) --------
  auto hidden = [&](const uint8_t* Ab, const uint8_t* Bb, float* outF,
                    uint8_t* spkN, float beta) {
    stage(0, Ab, Bb, 0, 0, 16);
    int p = 0;
    for (int ng = 0; ng < 8; ++ng) {
      v4i acc[7][2];
      #pragma unroll
      for (int m = 0; m < 7; ++m)
        #pragma unroll
        for (int n = 0; n < 2; ++n) { acc[m][n][0]=0; acc[m][n][1]=0; acc[m][n][2]=0; acc[m][n][3]=0; }
      for (int kc = 0; kc < 8; ++kc) {
        __syncthreads();                       // buf p ready (drains prior loads)
        if (kc < 7)      stage(p ^ 1, Ab, Bb, ng, kc + 1, 16);
        else if (ng < 7) stage(p ^ 1, Ab, Bb, ng + 1, 0, 16);
        const uint8_t* base = sAB + p * 30720;
        #pragma unroll
        for (int ks = 0; ks < 2; ++ks) {
          v4i bv0 = *(const v4i*)(base + (size_t)(14 + (2 * wave) * 2 + ks) * 1024 + lane * 16);
          v4i bv1 = *(const v4i*)(base + (size_t)(14 + (2 * wave + 1) * 2 + ks) * 1024 + lane * 16);
          #pragma unroll
          for (int m = 0; m < 7; ++m) {
            v4i av = *(const v4i*)(base + (size_t)(m * 2 + ks) * 1024 + lane * 16);
            acc[m][0] = __builtin_amdgcn_mfma_i32_16x16x64_i8(av, bv0, acc[m][0], 0, 0, 0);
            acc[m][1] = __builtin_amdgcn_mfma_i32_16x16x64_i8(av, bv1, acc[m][1], 0, 0, 0);
          }
        }
        p ^= 1;
      }
      __syncthreads();
      // epilogue: acc -> cbuf [j][t]
      #pragma unroll
      for (int m = 0; m < 7; ++m)
        #pragma unroll
        for (int n = 0; n < 2; ++n) {
          int col = (2 * wave + n) * 16 + lm;
          int row = m * 16 + lk * 4;
          uint32_t v01 = (uint32_t)(acc[m][n][0] & 0xffff) | ((uint32_t)acc[m][n][1] << 16);
          uint32_t v23 = (uint32_t)(acc[m][n][2] & 0xffff) | ((uint32_t)acc[m][n][3] << 16);
          *(uint32_t*)&cbuf16[col * 114 + row]     = v01;
          *(uint32_t*)&cbuf16[col * 114 + row + 2] = v23;
        }
      __syncthreads();
      // scan: register-preloaded, fully unrolled
      if (tid < 128) {
        int j = tid;
        uint32_t cr[50], nr[50];
        #pragma unroll
        for (int q = 0; q < 50; ++q) cr[q] = *(const uint32_t*)&cbuf16[j * 114 + 2 * q];
        #pragma unroll
        for (int q = 0; q < 50; ++q) nr[q] = *(const uint32_t*)&nprev16[2 * q];
        float m = 0.f;
        #pragma unroll
        for (int t = 0; t < NT; ++t) {
          uint32_t kv = (t & 1) ? (cr[t >> 1] >> 16) : (cr[t >> 1] & 0xffffu);
          uint32_t nv = (t & 1) ? (nr[t >> 1] >> 16) : (nr[t >> 1] & 0xffffu);
          float cur = fmaf(S2C, (float)kv, 0.001f * (float)nv);
          float rst = m > 1.0f ? 1.0f : 0.0f;
          m = fmaf(beta, m, cur) - rst;
          bool sp = (m - 1.0f) > 0.0f;
          __builtin_nontemporal_store(sp ? 1.0f : 0.0f,
              &outF[((size_t)t * NB + b) * NH + ng * 128 + j]);
          spkN[(size_t)t * 1024 + ng * 128 + j] = sp ? 1 : 0;
          unsigned long long bal = __ballot(sp);
          if (lane == 0) atomicAdd((unsigned int*)&nnextL[t], (unsigned)__popcll(bal));
        }
        #pragma unroll
        for (int t = NT; t < MT; ++t)
          spkN[(size_t)t * 1024 + ng * 128 + j] = 0;
      }
    }
  };

  hidden(SPK0b, ws + WS_K2B, out + O_SPK2, SPK1b, 0.85f);
  __syncthreads();
  if (tid < MT) { nprev16[tid] = (uint16_t)nnextL[tid]; nnextL[tid] = 0; }
  __syncthreads();
  hidden(SPK1b, ws + WS_K3B, out + O_SPK3, SPK0b, 0.8f);
  __syncthreads();
  if (tid < MT) { nprev16[tid] = (uint16_t)nnextL[tid]; }
  __syncthreads();

  // -------- layer 4 (N=48 pad of 35, zero-reset) --------
  {
    const uint8_t* Ab = SPK0b;
    const uint8_t* Bb = ws + WS_K4B;
    v4i acc[7];
    #pragma unroll
    for (int m = 0; m < 7; ++m) { acc[m][0]=0; acc[m][1]=0; acc[m][2]=0; acc[m][3]=0; }
    // stage with B rows 0..47 (nB=6 chunks), ng=0
    stage(0, Ab, Bb, 0, 0, 6);
    int p = 0;
    for (int kc = 0; kc < 8; ++kc) {
      __syncthreads();
      if (kc < 7) stage(p ^ 1, Ab, Bb, 0, kc + 1, 6);
      const uint8_t* base = sAB + p * 30720;
      if (wave < 3) {
        #pragma unroll
        for (int ks = 0; ks < 2; ++ks) {
          v4i bv = *(const v4i*)(base + (size_t)(14 + wave * 2 + ks) * 1024 + lane * 16);
          #pragma unroll
          for (int m = 0; m < 7; ++m) {
            v4i av = *(const v4i*)(base + (size_t)(m * 2 + ks) * 1024 + lane * 16);
            acc[m] = __builtin_amdgcn_mfma_i32_16x16x64_i8(av, bv, acc[m], 0, 0, 0);
          }
        }
      }
      p ^= 1;
    }
    __syncthreads();
    if (wave < 3) {
      #pragma unroll
      for (int m = 0; m < 7; ++m) {
        int col = wave * 16 + lm;
        int row = m * 16 + lk * 4;
        uint32_t v01 = (uint32_t)(acc[m][0] & 0xffff) | ((uint32_t)acc[m][1] << 16);
        uint32_t v23 = (uint32_t)(acc[m][2] & 0xffff) | ((uint32_t)acc[m][3] << 16);
        *(uint32_t*)&cbuf16[col * 114 + row]     = v01;
        *(uint32_t*)&cbuf16[col * 114 + row + 2] = v23;
      }
    }
    __syncthreads();
    if (tid < NOUT) {
      int j = tid;
      uint32_t cr[50], nr[50];
      #pragma unroll
      for (int q = 0; q < 50; ++q) cr[q] = *(const uint32_t*)&cbuf16[j * 114 + 2 * q];
      #pragma unroll
      for (int q = 0; q < 50; ++q) nr[q] = *(const uint32_t*)&nprev16[2 * q];
      float m = 0.f;
      #pragma unroll
      for (int t = 0; t < NT; ++t) {
        uint32_t kv = (t & 1) ? (cr[t >> 1] >> 16) : (cr[t >> 1] & 0xffffu);
        uint32_t nv = (t & 1) ? (nr[t >> 1] >> 16) : (nr[t >> 1] & 0xffffu);
        float cur = fmaf(S2C, (float)kv, 0.001f * (float)nv);
        float rst = m > 1.0f ? 1.0f : 0.0f;
        float bsv = fmaf(0.95f, m, cur);
        m = (rst > 0.0f) ? 0.0f : bsv;
        size_t rowO = ((size_t)t * NB + b) * NOUT + j;
        __builtin_nontemporal_store(((m - 1.0f) > 0.0f) ? 1.0f : 0.0f, &out[O_SPK4 + rowO]);
        __builtin_nontemporal_store(m, &out[O_MEM4 + rowO]);
      }
    }
  }
}

extern "C" void kernel_launch(void* const* d_in, const int* in_sizes, int n_in,
                              void* d_out, int out_size, void* d_ws, size_t ws_size,
                              hipStream_t stream)
{
  const float* x  = (const float*)d_in[0];
  const float* w1 = (const float*)d_in[1];
  const float* w2 = (const float*)d_in[2];
  const float* w3 = (const float*)d_in[3];
  const float* w4 = (const float*)d_in[4];
  float* out = (float*)d_out;
  uint8_t* ws = (uint8_t*)d_ws;

  hipLaunchKernelGGL(k_prep, dim3(9096), dim3(256), 0, stream, w1, w2, w3, w4, ws);
  hipLaunchKernelGGL(k_cur1, dim3(1600), dim3(256), 0, stream, x, ws, out);
  hipLaunchKernelGGL(k_scan1, dim3(1024), dim3(256), 0, stream, ws, out);
  hipLaunchKernelGGL(k_l234, dim3(256), dim3(256), 0, stream, ws, out);
}